// Round 6
// baseline (67.191 us; speedup 1.0000x reference)
//
#include <hip/hip_runtime.h>

typedef float f4 __attribute__((ext_vector_type(4)));

#define NPGL 256     // nodes per graph
#define EPGL 2048    // edges per graph
#define HIDD 64
#define KKEEP 128
#define NTH 1024

// float offset of float4-chunk c (0..15) of row n (swizzled within-row perm)
__device__ __forceinline__ int swz(int n, int c) {
  return (n << 6) + (((c ^ n) & 15) << 2);
}

__global__ void __launch_bounds__(NTH)
asap_fused(const float* __restrict__ x, const int* __restrict__ ei,
           const float* __restrict__ W1, const float* __restrict__ b1,
           const float* __restrict__ linW, const float* __restrict__ linb,
           const float* __restrict__ attW, const float* __restrict__ attb,
           const float* __restrict__ le1W, const float* __restrict__ le1b,
           const float* __restrict__ le2W,
           const float* __restrict__ le3W, const float* __restrict__ le3b,
           const float* __restrict__ W2, const float* __restrict__ b2,
           float* __restrict__ out, int Etot)
{
  const int g = blockIdx.x;
  const int tid = threadIdx.x;
  const int ln = tid & 15;          // chunk lane within 16-group
  const int grp = tid >> 4;         // 0..63 row group

  __shared__ __align__(16) float buf[NPGL * HIDD];   // 64KB: x -> h -> h1 -> xnew
  __shared__ __align__(16) float mskf[4096];         // 16KB: Imask/Rmask/conn/kept...
  __shared__ __align__(16) float esc[EPGL];          // 8KB: coefE -> scores -> partials
  __shared__ unsigned char csrc[EPGL];               // 2KB CSR src (by dst)
  __shared__ int rowst[NPGL + 1];
  __shared__ int cnt[NPGL];
  __shared__ float dinv_[NPGL];                      // conv1 norm -> LEConv c3
  __shared__ float sA[NPGL], sB[NPGL];
  __shared__ float rsf[NPGL];                        // fitness
  __shared__ float u_[HIDD];
  __shared__ float wsum[HIDD];
  __shared__ int scanw[4];
  __shared__ float c0s;

  unsigned long long* Imask = (unsigned long long*)mskf;           // [1024]
  unsigned long long* Rmask = ((unsigned long long*)mskf) + 1024;  // [512]
  unsigned long long* conn  = ((unsigned long long*)mskf) + 1536;  // [256]
  int*   kept = (int*)(mskf + 3584);                               // [128]
  float* d2A  = mskf + 3712;                                       // [128]
  float* cA   = mskf + 3840;                                       // [128]

  const int ebase = g * EPGL;
  const int nbase = g * NPGL;

  // ---------------- Phase 0: CSR build + x stage + Imask ----------------
  ((unsigned long long*)mskf)[tid] = 0ull;           // zero Imask region
  if (tid < NPGL) cnt[tid] = 0;
  __syncthreads();

  int es[2], ed[2];
#pragma unroll
  for (int i = 0; i < 2; ++i) {
    const int e = tid + i * NTH;
    es[i] = ei[ebase + e] - nbase;
    ed[i] = ei[Etot + ebase + e] - nbase;
    atomicAdd(&cnt[ed[i]], 1);
  }
  // stage x -> buf (swizzled); completes before ph1 reads (scan barrier below)
  {
    const f4* xg = (const f4*)(x + (size_t)nbase * HIDD);
#pragma unroll
    for (int ii = 0; ii < 4; ++ii) {
      const int i = tid + ii * NTH;
      *(f4*)&buf[swz(i >> 4, i & 15)] = xg[i];
    }
  }
  __syncthreads();

  if (tid < NPGL) {                 // wave-level inclusive scan + dinv
    const int myc = cnt[tid];
    int vscan = myc;
#pragma unroll
    for (int off = 1; off < 64; off <<= 1) {
      const int up = __shfl_up(vscan, off, 64);
      if ((tid & 63) >= off) vscan += up;
    }
    if ((tid & 63) == 63) scanw[tid >> 6] = vscan;
    dinv_[tid] = rsqrtf((float)myc + 1.0f);
    // second step after cross-wave totals
    __syncthreads();
    int add = 0;
    const int w = tid >> 6;
    for (int ww = 0; ww < w; ++ww) add += scanw[ww];
    const int incl = vscan + add;
    rowst[tid + 1] = incl;
    cnt[tid] = incl - myc;          // exclusive scan = scatter cursor
    if (tid == 0) rowst[0] = 0;
  } else {
    __syncthreads();
  }
  if (tid < HIDD) {                 // u = lin_W @ attW[:64]
    float a = 0.f;
    for (int f = 0; f < HIDD; ++f) a += linW[tid * HIDD + f] * attW[f];
    u_[tid] = a;
  }
  if (tid == 0) {
    float a = 0.f;
    for (int f = 0; f < HIDD; ++f) a += linb[f] * attW[f];
    c0s = a + attb[0];
  }
  __syncthreads();

  // scatter (+ per-edge GCN coef into esc) + Imask bits
#pragma unroll
  for (int i = 0; i < 2; ++i) {
    const int p = atomicAdd(&cnt[ed[i]], 1);
    csrc[p] = (unsigned char)es[i];
    esc[p] = dinv_[es[i]] * dinv_[ed[i]];
  }
  if (tid < NPGL) atomicOr(&Imask[tid * 4 + (tid >> 6)], 1ull << (tid & 63));
#pragma unroll
  for (int i = 0; i < 2; ++i)
    atomicOr(&Imask[ed[i] * 4 + (es[i] >> 6)], 1ull << (es[i] & 63));
  __syncthreads();

  // ---------------- Phase 1: h = x @ W1 (W1 scalar loads, packed FMA) ----------------
  {
    const int wv = tid >> 6;
    const int r  = ((wv & 3) << 6) + (tid & 63);
    const int fc = __builtin_amdgcn_readfirstlane(wv >> 2);
    const float* __restrict__ Wg = W1 + fc * 16;
    f4 acc[4];
#pragma unroll
    for (int c = 0; c < 4; ++c) acc[c] = f4{0.f, 0.f, 0.f, 0.f};
#pragma unroll
    for (int p = 0; p < 4; ++p) {
      f4 xa[4];
#pragma unroll
      for (int c = 0; c < 4; ++c) xa[c] = *(const f4*)&buf[swz(r, p * 4 + c)];
#pragma unroll
      for (int kk = 0; kk < 16; ++kk) {
        const int k = p * 16 + kk;
        const float xv = ((const float*)xa)[kk];
        const float* __restrict__ Wk = Wg + k * HIDD;  // uniform -> s_load
#pragma unroll
        for (int c = 0; c < 4; ++c)
          acc[c] += xv * *(const f4*)(Wk + c * 4);
      }
    }
    __syncthreads();                // all x reads before h overwrite
#pragma unroll
    for (int c = 0; c < 4; ++c) *(f4*)&buf[swz(r, fc * 4 + c)] = acc[c];
  }
  __syncthreads();

  // ---------------- Phase 2: h1 = relu(GCN agg), 16 lanes/row ----------------
  {
    f4 hacc[4];
#pragma unroll
    for (int p = 0; p < 4; ++p) {
      const int d = (p << 6) + grp;
      const float dd = dinv_[d];
      const f4 own = *(const f4*)&buf[swz(d, ln)];
      const f4 bv = *(const f4*)&b1[ln * 4];
      f4 a = own * (dd * dd) + bv;
      const int s0 = rowst[d], s1 = rowst[d + 1];
      int it = s0;
      for (; it + 2 <= s1; it += 2) {
        const int sa_ = csrc[it], sb_ = csrc[it + 1];
        const float ca_ = esc[it], cb_ = esc[it + 1];
        const f4 va = *(const f4*)&buf[swz(sa_, ln)];
        const f4 vb = *(const f4*)&buf[swz(sb_, ln)];
        a += ca_ * va + cb_ * vb;
      }
      if (it < s1) {
        const int s = csrc[it];
        a += esc[it] * *(const f4*)&buf[swz(s, ln)];
      }
      a = __builtin_elementwise_max(a, f4{0.f, 0.f, 0.f, 0.f});
      // sB[d] = dot(h1[d], attW2) folded here (row already in regs)
      const f4 aw = *(const f4*)&attW[HIDD + ln * 4];
      float sBp = a.x * aw.x + a.y * aw.y + a.z * aw.z + a.w * aw.w;
      sBp += __shfl_xor(sBp, 1); sBp += __shfl_xor(sBp, 2);
      sBp += __shfl_xor(sBp, 4); sBp += __shfl_xor(sBp, 8);
      if (ln == 0) sB[d] = sBp;
      hacc[p] = a;
    }
    __syncthreads();
#pragma unroll
    for (int p = 0; p < 4; ++p)
      *(f4*)&buf[swz((p << 6) + grp, ln)] = hacc[p];
  }
  __syncthreads();

  // ---------------- Phase 3+4+5 merged: max-gather, softmax, xnew ----------------
  {
    f4 xacc[4];
#pragma unroll
    for (int p = 0; p < 4; ++p) {
      const int d = (p << 6) + grp;
      const int s0 = rowst[d], s1 = rowst[d + 1];
      const int deg = s1 - s0;
      const f4 own = *(const f4*)&buf[swz(d, ln)];
      f4 mx = own;
      f4 cch[8];
      // pass A: elementwise max + register cache of first 8 rows
#pragma unroll
      for (int j = 0; j < 8; ++j) {
        if (j < deg) {
          const int s = csrc[s0 + j];
          const f4 v = *(const f4*)&buf[swz(s, ln)];
          cch[j] = v;
          mx = __builtin_elementwise_max(mx, v);
        }
      }
      for (int it = s0 + 8; it < s1; ++it) {
        const int s = csrc[it];
        mx = __builtin_elementwise_max(mx, *(const f4*)&buf[swz(s, ln)]);
      }
      // sA = c0 + dot(max, u)
      const f4 uu = *(const f4*)&u_[ln * 4];
      float sAv = mx.x * uu.x + mx.y * uu.y + mx.z * uu.z + mx.w * uu.w;
      sAv += __shfl_xor(sAv, 1); sAv += __shfl_xor(sAv, 2);
      sAv += __shfl_xor(sAv, 4); sAv += __shfl_xor(sAv, 8);
      const float sa = c0s + sAv;
      // softmax over edges (strided by ln)
      float scS = sa + sB[d];
      scS = scS >= 0.f ? scS : 0.2f * scS;
      float mxv = scS;
      for (int t = s0 + ln; t < s1; t += 16) {
        float sc = sa + sB[csrc[t]];
        sc = sc >= 0.f ? sc : 0.2f * sc;
        mxv = fmaxf(mxv, sc);
      }
      mxv = fmaxf(mxv, __shfl_xor(mxv, 1));
      mxv = fmaxf(mxv, __shfl_xor(mxv, 2));
      mxv = fmaxf(mxv, __shfl_xor(mxv, 4));
      mxv = fmaxf(mxv, __shfl_xor(mxv, 8));
      float sum = 0.f;
      for (int t = s0 + ln; t < s1; t += 16) {
        float sc = sa + sB[csrc[t]];
        sc = sc >= 0.f ? sc : 0.2f * sc;
        const float e = __expf(sc - mxv);
        esc[t] = e;
        sum += e;
      }
      sum += __shfl_xor(sum, 1); sum += __shfl_xor(sum, 2);
      sum += __shfl_xor(sum, 4); sum += __shfl_xor(sum, 8);
      const float esf = __expf(scS - mxv);
      const float rs = 1.0f / (esf + sum + 1e-16f);
      // make this wave's esc writes readable by its other lanes
      asm volatile("s_waitcnt lgkmcnt(0)" ::: "memory");
      // pass B: weighted sum (cached rows free, tail re-read)
      f4 a = esf * own;
#pragma unroll
      for (int j = 0; j < 8; ++j) {
        if (j < deg) a += esc[s0 + j] * cch[j];
      }
      for (int it = s0 + 8; it < s1; ++it) {
        const int s = csrc[it];
        a += esc[it] * *(const f4*)&buf[swz(s, ln)];
      }
      xacc[p] = a * rs;
    }
    __syncthreads();
#pragma unroll
    for (int p = 0; p < 4; ++p)
      *(f4*)&buf[swz((p << 6) + grp, ln)] = xacc[p];
  }
  __syncthreads();

  // ---------------- Phase 6: LEConv dots (16 lanes/row) + fitness ----------------
#pragma unroll
  for (int p = 0; p < 4; ++p) {
    const int n = (p << 6) + grp;
    const f4 v = *(const f4*)&buf[swz(n, ln)];
    const f4 w1v = *(const f4*)&le1W[ln * 4];
    const f4 w2v = *(const f4*)&le2W[ln * 4];
    const f4 w3v = *(const f4*)&le3W[ln * 4];
    float av = v.x * w1v.x + v.y * w1v.y + v.z * w1v.z + v.w * w1v.w;
    float bv = v.x * w2v.x + v.y * w2v.y + v.z * w2v.z + v.w * w2v.w;
    float cv = v.x * w3v.x + v.y * w3v.y + v.z * w3v.z + v.w * w3v.w;
    av += __shfl_xor(av, 1); av += __shfl_xor(av, 2);
    av += __shfl_xor(av, 4); av += __shfl_xor(av, 8);
    bv += __shfl_xor(bv, 1); bv += __shfl_xor(bv, 2);
    bv += __shfl_xor(bv, 4); bv += __shfl_xor(bv, 8);
    cv += __shfl_xor(cv, 1); cv += __shfl_xor(cv, 2);
    cv += __shfl_xor(cv, 4); cv += __shfl_xor(cv, 8);
    if (ln == 0) {
      sA[n] = av + le1b[0];
      sB[n] = bv;
      dinv_[n] = cv + le3b[0];
    }
  }
  __syncthreads();
  {
    const int d = tid >> 2, q = tid & 3;
    const int s0 = rowst[d], s1 = rowst[d + 1];
    float fp = 0.f;
    for (int it = s0 + q; it < s1; it += 4) fp += sA[csrc[it]];
    fp += __shfl_xor(fp, 1); fp += __shfl_xor(fp, 2);
    if (q == 0) {
      float f = sA[d] + fp;
      f -= (float)(s1 - s0 + 1) * sB[d];
      f += dinv_[d];
      float sg;
      if (f >= 0.f) sg = 1.f / (1.f + expf(-f));
      else { const float t = expf(f); sg = t / (1.f + t); }
      rsf[d] = sg;
    }
  }
  __syncthreads();

  // ---------------- Phase 7: top-K by rank ----------------
  {
    const int n = tid >> 2, q = tid & 3;
    const float fn = rsf[n];
    int r = 0;
    for (int m = q * 64; m < q * 64 + 64; ++m) {
      const float fm = rsf[m];
      r += ((fm > fn) || (fm == fn && m < n)) ? 1 : 0;
    }
    r += __shfl_xor(r, 1); r += __shfl_xor(r, 2);
    if (q == 0 && r < KKEEP) kept[r] = n;
  }
  __syncthreads();

  // ---------------- Phase 9: Rmask / conn ----------------
  if (tid < KKEEP * 4) {
    const int q = tid >> 2, w = tid & 3;
    const int kq = kept[q];
    unsigned long long acc = 0ull;
#pragma unroll
    for (int ww = 0; ww < 4; ++ww) {
      unsigned long long bits = Imask[kq * 4 + ww];
      while (bits) {
        const int m = (ww << 6) + __builtin_ctzll(bits);
        bits &= bits - 1;
        acc |= Imask[m * 4 + w];
      }
    }
    Rmask[q * 4 + w] = acc;
  }
  __syncthreads();
  if (tid < KKEEP * 2) conn[tid] = 0ull;
  __syncthreads();
  if (tid < KKEEP * 4) {
    const int p = tid >> 2, wb = tid & 3;
    const int kp = kept[p];
    const unsigned long long I0 = Imask[kp * 4 + 0], I1 = Imask[kp * 4 + 1],
                             I2 = Imask[kp * 4 + 2], I3 = Imask[kp * 4 + 3];
    unsigned long long bits = 0ull;
    for (int j = 0; j < 32; ++j) {
      const int q = wb * 32 + j;
      if (q == p) continue;
      const unsigned long long* R = &Rmask[q * 4];
      if ((I0 & R[0]) | (I1 & R[1]) | (I2 & R[2]) | (I3 & R[3]))
        bits |= 1ull << (q & 63);
    }
    atomicOr(&conn[p * 2 + (wb >> 1)], bits);
  }
  __syncthreads();

  // ---------------- Phase 10: deg2, d2, c[s] ----------------
  if (tid < KKEEP) {
    const int q = tid;
    const int w = q >> 6;
    const unsigned long long bq = 1ull << (q & 63);
    int deg = 1;
    for (int p = 0; p < KKEEP; ++p) deg += (conn[p * 2 + w] & bq) ? 1 : 0;
    d2A[q] = rsqrtf((float)deg);
  }
  __syncthreads();
  if (tid < KKEEP) {
    const int s = tid;
    float acc = d2A[s];
#pragma unroll
    for (int w = 0; w < 2; ++w) {
      unsigned long long bits = conn[s * 2 + w];
      while (bits) {
        const int d = (w << 6) + __builtin_ctzll(bits);
        bits &= bits - 1;
        acc += d2A[d];
      }
    }
    cA[s] = d2A[s] * acc * rsf[kept[s]] * (1.0f / (float)KKEEP);
  }
  __syncthreads();

  // ---------------- Phase 11: wsum[k] = sum_s cA[s]*xnew[kept[s],k]; out ----------------
  {
    const int f = tid & 63, blk = tid >> 6;   // 16 blocks of 8 kept nodes
    float p = 0.f;
    for (int j = 0; j < 8; ++j) {
      const int s = blk * 8 + j;
      const int ks = kept[s];
      const int off = (ks << 6) + ((((f >> 2) ^ ks) & 15) << 2) + (f & 3);
      p += cA[s] * buf[off];
    }
    esc[blk * 64 + f] = p;
  }
  __syncthreads();
  if (tid < HIDD) {
    float s = 0.f;
#pragma unroll
    for (int b = 0; b < 16; ++b) s += esc[b * 64 + tid];
    wsum[tid] = s;
  }
  __syncthreads();
  if (tid < HIDD) {
    float o = b2[tid];
    for (int k = 0; k < HIDD; ++k) o += wsum[k] * W2[k * HIDD + tid];
    out[(size_t)g * HIDD + tid] = o;
  }
}

extern "C" void kernel_launch(void* const* d_in, const int* in_sizes, int n_in,
                              void* d_out, int out_size, void* d_ws, size_t ws_size,
                              hipStream_t stream) {
  (void)n_in; (void)out_size; (void)d_ws; (void)ws_size;
  const float* x    = (const float*)d_in[0];
  const int*   ei   = (const int*)d_in[1];
  // d_in[2] = batch (contiguous equal graphs; unused)
  const float* W1   = (const float*)d_in[3];
  const float* b1   = (const float*)d_in[4];
  const float* linW = (const float*)d_in[5];
  const float* linb = (const float*)d_in[6];
  const float* attW = (const float*)d_in[7];
  const float* attb = (const float*)d_in[8];
  const float* le1W = (const float*)d_in[9];
  const float* le1b = (const float*)d_in[10];
  const float* le2W = (const float*)d_in[11];
  const float* le3W = (const float*)d_in[12];
  const float* le3b = (const float*)d_in[13];
  const float* W2   = (const float*)d_in[14];
  const float* b2   = (const float*)d_in[15];
  const int Etot = in_sizes[1] / 2;   // 524288
  const int nGraphs = 256;

  asap_fused<<<dim3(nGraphs), dim3(NTH), 0, stream>>>(
      x, ei, W1, b1, linW, linb, attW, attb, le1W, le1b, le2W, le3W, le3b,
      W2, b2, (float*)d_out, Etot);
}

// Round 7
// 58.243 us; speedup vs baseline: 1.1536x; 1.1536x over previous
//
#include <hip/hip_runtime.h>

typedef float f4 __attribute__((ext_vector_type(4)));
typedef unsigned long long u64;

#define NPGL 256     // nodes per graph
#define EPGL 2048    // edges per graph
#define HIDD 64
#define KKEEP 128
#define NTH 1024

// float offset of float4-chunk c (0..15) of row n in the swizzled LDS tile
__device__ __forceinline__ int swz(int n, int c) {
  return (n << 6) + ((((c ^ n) ^ (n >> 4)) & 15) << 2);
}

__global__ void __launch_bounds__(NTH)
asap_fused(const float* __restrict__ x, const int* __restrict__ ei,
           const float* __restrict__ W1, const float* __restrict__ b1,
           const float* __restrict__ linW, const float* __restrict__ linb,
           const float* __restrict__ attW, const float* __restrict__ attb,
           const float* __restrict__ le1W, const float* __restrict__ le1b,
           const float* __restrict__ le2W,
           const float* __restrict__ le3W, const float* __restrict__ le3b,
           const float* __restrict__ W2, const float* __restrict__ b2,
           float* __restrict__ out, int Etot)
{
  const int g = blockIdx.x;
  const int tid = threadIdx.x;

  __shared__ __align__(16) float buf[NPGL * HIDD];   // 64KB: x -> h -> h1 -> xnew
  __shared__ __align__(16) float mskf[4096];         // 16KB: Imask/Rmask/conn/kept...
  __shared__ __align__(16) float esc[EPGL];          // 8KB: exp scores / partials
  __shared__ __align__(8) unsigned char csrc[4096];  // 4KB padded CSR src (by dst)
  __shared__ unsigned short rowstU[NPGL + 1];        // unpadded row starts
  __shared__ unsigned short rowstP[NPGL + 1];        // 8-padded row starts
  __shared__ int cnt[NPGL];                          // counts -> cursors -> deg
  __shared__ float dinv_[NPGL];                      // conv1 norm -> LEConv c3
  __shared__ float sA[NPGL], sB[NPGL];
  __shared__ float rsf[NPGL];                        // fitness
  __shared__ float u_[HIDD], wsum[HIDD];
  __shared__ int scanw[4], scanwP[4];
  __shared__ float c0s;

  u64* Imask = (u64*)mskf;                 // [1024] = 8KB
  u64* Rmask = ((u64*)mskf) + 1024;        // [512]  = 4KB
  u64* conn  = ((u64*)mskf) + 1536;        // [256]  = 2KB
  int*   kept = (int*)(mskf + 3584);       // [128]
  float* d2A  = mskf + 3712;               // [128]
  float* cA   = mskf + 3840;               // [128]

  const int ebase = g * EPGL;
  const int nbase = g * NPGL;

  // ---------------- Phase 0: CSR build (padded) + x stage + Imask ----------------
  ((u64*)mskf)[tid] = 0ull;                          // zero Imask (8KB)
  if (tid < NPGL) { cnt[tid] = 0; ((u64*)mskf)[1536 + tid] = 0ull; }  // zero conn
  __syncthreads();

  int es[2], ed[2];
#pragma unroll
  for (int i = 0; i < 2; ++i) {
    const int e = tid + i * NTH;
    es[i] = ei[ebase + e] - nbase;
    ed[i] = ei[Etot + ebase + e] - nbase;
    atomicAdd(&cnt[ed[i]], 1);
  }
  // stage x -> buf (swizzled)
  {
    const f4* xg = (const f4*)(x + (size_t)nbase * HIDD);
#pragma unroll
    for (int ii = 0; ii < 4; ++ii) {
      const int i = tid + ii * NTH;
      *(f4*)&buf[swz(i >> 4, i & 15)] = xg[i];
    }
  }
  __syncthreads();

  int sU = 0, sP = 0, mU = 0;
  if (tid < NPGL) {                 // dual wave scan: unpadded + padded sizes
    mU = cnt[tid];
    const int mP = (mU + 7) & ~7;
    sU = mU; sP = mP;
#pragma unroll
    for (int off = 1; off < 64; off <<= 1) {
      const int uU = __shfl_up(sU, off, 64);
      const int uP = __shfl_up(sP, off, 64);
      if ((tid & 63) >= off) { sU += uU; sP += uP; }
    }
    if ((tid & 63) == 63) { scanw[tid >> 6] = sU; scanwP[tid >> 6] = sP; }
  }
  __syncthreads();
  if (tid < NPGL) {
    int aU = 0, aP = 0;
    const int w = tid >> 6;
    for (int ww = 0; ww < w; ++ww) { aU += scanw[ww]; aP += scanwP[ww]; }
    rowstU[tid + 1] = (unsigned short)(sU + aU);
    rowstP[tid + 1] = (unsigned short)(sP + aP);
    if (tid == 0) { rowstU[0] = 0; rowstP[0] = 0; }
    cnt[tid] = 0;                   // reset to use as arrival cursor
    dinv_[tid] = rsqrtf((float)mU + 1.0f);
  }
  if (tid < HIDD) {                 // u = lin_W @ attW[:64]
    float a = 0.f;
    for (int f = 0; f < HIDD; ++f) a += linW[tid * HIDD + f] * attW[f];
    u_[tid] = a;
  }
  if (tid == 0) {
    float a = 0.f;
    for (int f = 0; f < HIDD; ++f) a += linb[f] * attW[f];
    c0s = a + attb[0];
  }
  __syncthreads();

  // scatter into padded CSR + Imask bits
#pragma unroll
  for (int i = 0; i < 2; ++i) {
    const int j = atomicAdd(&cnt[ed[i]], 1);
    csrc[(int)rowstP[ed[i]] + j] = (unsigned char)es[i];
  }
  if (tid < NPGL) atomicOr(&Imask[tid * 4 + (tid >> 6)], 1ull << (tid & 63));
#pragma unroll
  for (int i = 0; i < 2; ++i)
    atomicOr(&Imask[ed[i] * 4 + (es[i] >> 6)], 1ull << (es[i] & 63));
  __syncthreads();

  // ---------------- Phase 1: h = x @ W1 (W1 via scalar loads) ----------------
  {
    const int wv = tid >> 6;
    const int r  = ((wv & 3) << 6) + (tid & 63);
    const int fc = __builtin_amdgcn_readfirstlane(wv >> 2);
    const float* __restrict__ Wg = W1 + fc * 16;
    f4 acc[4];
#pragma unroll
    for (int c = 0; c < 4; ++c) acc[c] = f4{0.f, 0.f, 0.f, 0.f};
#pragma unroll
    for (int p = 0; p < 4; ++p) {
      f4 xa[4];
#pragma unroll
      for (int c = 0; c < 4; ++c) xa[c] = *(const f4*)&buf[swz(r, p * 4 + c)];
#pragma unroll
      for (int kk = 0; kk < 16; ++kk) {
        const int k = p * 16 + kk;
        const float xv = ((const float*)xa)[kk];
        const float* __restrict__ Wk = Wg + k * HIDD;   // uniform -> s_load
#pragma unroll
        for (int c = 0; c < 4; ++c)
          acc[c] += xv * *(const f4*)(Wk + c * 4);
      }
    }
    __syncthreads();                // all x reads before h overwrite
#pragma unroll
    for (int c = 0; c < 4; ++c) *(f4*)&buf[swz(r, fc * 4 + c)] = acc[c];
  }
  __syncthreads();

  // ---------------- Phase 2: h1 = relu(GCN agg) + sB fold ----------------
  {
    const int d = tid >> 2, hh = tid & 3;
    const float dd = dinv_[d];
    const int deg = cnt[d];
    const int p0 = rowstP[d];
    f4 acc[4];
#pragma unroll
    for (int j = 0; j < 4; ++j) {
      const int c = hh + 4 * j;
      acc[j] = *(const f4*)&buf[swz(d, c)] * (dd * dd) + *(const f4*)&b1[4 * c];
    }
    const int nb = deg >> 3;
    int j8 = 0;
    for (int b = 0; b < nb; ++b, j8 += 8) {
      const u64 bits = *(const u64*)(csrc + p0 + j8);
#pragma unroll
      for (int t = 0; t < 8; ++t) {
        const int s = (int)((bits >> (8 * t)) & 255);
        const float cf = dinv_[s] * dd;
#pragma unroll
        for (int j = 0; j < 4; ++j)
          acc[j] += cf * *(const f4*)&buf[swz(s, hh + 4 * j)];
      }
    }
    const int rem = deg & 7;
    if (rem) {
      const u64 bits = *(const u64*)(csrc + p0 + j8);
      for (int t = 0; t < rem; ++t) {
        const int s = (int)((bits >> (8 * t)) & 255);
        const float cf = dinv_[s] * dd;
#pragma unroll
        for (int j = 0; j < 4; ++j)
          acc[j] += cf * *(const f4*)&buf[swz(s, hh + 4 * j)];
      }
    }
    float sBp = 0.f;
#pragma unroll
    for (int j = 0; j < 4; ++j) {
      acc[j] = __builtin_elementwise_max(acc[j], f4{0.f, 0.f, 0.f, 0.f});
      const f4 aw = *(const f4*)&attW[HIDD + 4 * (hh + 4 * j)];
      sBp += acc[j].x * aw.x + acc[j].y * aw.y + acc[j].z * aw.z + acc[j].w * aw.w;
    }
    sBp += __shfl_xor(sBp, 1); sBp += __shfl_xor(sBp, 2);
    if (hh == 0) sB[d] = sBp;
    __syncthreads();
#pragma unroll
    for (int j = 0; j < 4; ++j) *(f4*)&buf[swz(d, hh + 4 * j)] = acc[j];
  }
  __syncthreads();

  // ---------------- Phase 3+4+5: seg-max -> sA -> softmax -> xnew ----------------
  {
    const int d = tid >> 2, hh = tid & 3;
    const int deg = cnt[d];
    const int p0 = rowstP[d];
    const int q0 = rowstU[d];
    f4 own[4], mx[4];
#pragma unroll
    for (int j = 0; j < 4; ++j) {
      own[j] = *(const f4*)&buf[swz(d, hh + 4 * j)];
      mx[j] = own[j];
    }
    // seg-max gather (indices batched in regs)
    const int nb = deg >> 3;
    int j8 = 0;
    for (int b = 0; b < nb; ++b, j8 += 8) {
      const u64 bits = *(const u64*)(csrc + p0 + j8);
#pragma unroll
      for (int t = 0; t < 8; ++t) {
        const int s = (int)((bits >> (8 * t)) & 255);
#pragma unroll
        for (int j = 0; j < 4; ++j)
          mx[j] = __builtin_elementwise_max(mx[j], *(const f4*)&buf[swz(s, hh + 4 * j)]);
      }
    }
    const int rem = deg & 7;
    if (rem) {
      const u64 bits = *(const u64*)(csrc + p0 + j8);
      for (int t = 0; t < rem; ++t) {
        const int s = (int)((bits >> (8 * t)) & 255);
#pragma unroll
        for (int j = 0; j < 4; ++j)
          mx[j] = __builtin_elementwise_max(mx[j], *(const f4*)&buf[swz(s, hh + 4 * j)]);
      }
    }
    float sAv = 0.f;
#pragma unroll
    for (int j = 0; j < 4; ++j) {
      const f4 uu = *(const f4*)&u_[4 * (hh + 4 * j)];
      sAv += mx[j].x * uu.x + mx[j].y * uu.y + mx[j].z * uu.z + mx[j].w * uu.w;
    }
    sAv += __shfl_xor(sAv, 1); sAv += __shfl_xor(sAv, 2);
    const float sa = c0s + sAv;
    // softmax over edges (4-lane strided)
    float scS = sa + sB[d];
    scS = scS >= 0.f ? scS : 0.2f * scS;
    float mxv = scS;
#pragma unroll 4
    for (int t = hh; t < deg; t += 4) {
      float sc = sa + sB[csrc[p0 + t]];
      sc = sc >= 0.f ? sc : 0.2f * sc;
      mxv = fmaxf(mxv, sc);
    }
    mxv = fmaxf(mxv, __shfl_xor(mxv, 1));
    mxv = fmaxf(mxv, __shfl_xor(mxv, 2));
    float sum = 0.f;
#pragma unroll 4
    for (int t = hh; t < deg; t += 4) {
      float sc = sa + sB[csrc[p0 + t]];
      sc = sc >= 0.f ? sc : 0.2f * sc;
      const float e = __expf(sc - mxv);
      esc[q0 + t] = e;
      sum += e;
    }
    sum += __shfl_xor(sum, 1); sum += __shfl_xor(sum, 2);
    const float esf = __expf(scS - mxv);
    const float rs = 1.0f / (esf + sum + 1e-16f);
    // ensure this wave's esc writes are complete before cross-lane reads
    asm volatile("s_waitcnt lgkmcnt(0)" ::: "memory");
    // weighted gather
    f4 a[4];
#pragma unroll
    for (int j = 0; j < 4; ++j) a[j] = esf * own[j];
    j8 = 0;
    for (int b = 0; b < nb; ++b, j8 += 8) {
      const u64 bits = *(const u64*)(csrc + p0 + j8);
#pragma unroll
      for (int t = 0; t < 8; ++t) {
        const int s = (int)((bits >> (8 * t)) & 255);
        const float e = esc[q0 + j8 + t];
#pragma unroll
        for (int j = 0; j < 4; ++j)
          a[j] += e * *(const f4*)&buf[swz(s, hh + 4 * j)];
      }
    }
    if (rem) {
      const u64 bits = *(const u64*)(csrc + p0 + j8);
      for (int t = 0; t < rem; ++t) {
        const int s = (int)((bits >> (8 * t)) & 255);
        const float e = esc[q0 + j8 + t];
#pragma unroll
        for (int j = 0; j < 4; ++j)
          a[j] += e * *(const f4*)&buf[swz(s, hh + 4 * j)];
      }
    }
#pragma unroll
    for (int j = 0; j < 4; ++j) a[j] *= rs;
    __syncthreads();
#pragma unroll
    for (int j = 0; j < 4; ++j) *(f4*)&buf[swz(d, hh + 4 * j)] = a[j];
  }
  __syncthreads();

  // ---------------- Phase 6: LEConv dots + fitness ----------------
  {
    const int n = tid >> 2, q = tid & 3;
    float av = 0.f, bv = 0.f, cv = 0.f;
#pragma unroll
    for (int j = 0; j < 4; ++j) {
      const int c = q + 4 * j;
      const f4 v = *(const f4*)&buf[swz(n, c)];
      const int k = c * 4;
      av += v.x * le1W[k] + v.y * le1W[k + 1] + v.z * le1W[k + 2] + v.w * le1W[k + 3];
      bv += v.x * le2W[k] + v.y * le2W[k + 1] + v.z * le2W[k + 2] + v.w * le2W[k + 3];
      cv += v.x * le3W[k] + v.y * le3W[k + 1] + v.z * le3W[k + 2] + v.w * le3W[k + 3];
    }
    av += __shfl_xor(av, 1); av += __shfl_xor(av, 2);
    bv += __shfl_xor(bv, 1); bv += __shfl_xor(bv, 2);
    cv += __shfl_xor(cv, 1); cv += __shfl_xor(cv, 2);
    if (q == 0) {
      sA[n] = av + le1b[0];
      sB[n] = bv;
      dinv_[n] = cv + le3b[0];
    }
  }
  __syncthreads();
  {
    const int d = tid >> 2, q = tid & 3;
    const int deg = cnt[d];
    const int p0 = rowstP[d];
    float fp = 0.f;
#pragma unroll 4
    for (int t = q; t < deg; t += 4) fp += sA[csrc[p0 + t]];
    fp += __shfl_xor(fp, 1); fp += __shfl_xor(fp, 2);
    if (q == 0) {
      float f = sA[d] + fp;
      f -= (float)(deg + 1) * sB[d];
      f += dinv_[d];
      float sg;
      if (f >= 0.f) sg = 1.f / (1.f + expf(-f));
      else { const float t2 = expf(f); sg = t2 / (1.f + t2); }
      rsf[d] = sg;
    }
  }
  __syncthreads();

  // ---------------- Phase 7: top-K by rank ----------------
  {
    const int n = tid >> 2, q = tid & 3;
    const float fn = rsf[n];
    int r = 0;
    for (int m = q * 64; m < q * 64 + 64; ++m) {
      const float fm = rsf[m];
      r += ((fm > fn) || (fm == fn && m < n)) ? 1 : 0;
    }
    r += __shfl_xor(r, 1); r += __shfl_xor(r, 2);
    if (q == 0 && r < KKEEP) kept[r] = n;
  }
  __syncthreads();

  // ---------------- Phase 9: Rmask / conn ----------------
  if (tid < KKEEP * 4) {
    const int q = tid >> 2, w = tid & 3;
    const int kq = kept[q];
    u64 acc = 0ull;
#pragma unroll
    for (int ww = 0; ww < 4; ++ww) {
      u64 bits = Imask[kq * 4 + ww];
      while (bits) {
        const int m = (ww << 6) + __builtin_ctzll(bits);
        bits &= bits - 1;
        acc |= Imask[m * 4 + w];
      }
    }
    Rmask[q * 4 + w] = acc;
  }
  __syncthreads();
  if (tid < KKEEP * 4) {
    const int p = tid >> 2, wb = tid & 3;
    const int kp = kept[p];
    const u64 I0 = Imask[kp * 4 + 0], I1 = Imask[kp * 4 + 1],
              I2 = Imask[kp * 4 + 2], I3 = Imask[kp * 4 + 3];
    u64 bits = 0ull;
    for (int j = 0; j < 32; ++j) {
      const int q = wb * 32 + j;
      if (q == p) continue;
      const u64* R = &Rmask[q * 4];
      if ((I0 & R[0]) | (I1 & R[1]) | (I2 & R[2]) | (I3 & R[3]))
        bits |= 1ull << (q & 63);
    }
    atomicOr(&conn[p * 2 + (wb >> 1)], bits);
  }
  __syncthreads();

  // ---------------- Phase 10: deg2, d2 (512 thr), cA (512 thr) ----------------
  if (tid < KKEEP * 4) {
    const int q = tid >> 2, h = tid & 3;
    const int w = q >> 6, sh = q & 63;
    int c = 0;
    for (int p = h * 32; p < h * 32 + 32; ++p)
      c += (int)((conn[p * 2 + w] >> sh) & 1ull);
    c += __shfl_xor(c, 1); c += __shfl_xor(c, 2);
    if (h == 0) d2A[q] = rsqrtf((float)(c + 1));
  }
  __syncthreads();
  if (tid < KKEEP * 4) {
    const int s = tid >> 2, h = tid & 3;
    unsigned int b32 = (unsigned int)(conn[s * 2 + (h >> 1)] >> (32 * (h & 1)));
    const int base = ((h >> 1) << 6) + ((h & 1) << 5);
    float acc = 0.f;
    while (b32) {
      const int d_ = base + __builtin_ctz(b32);
      b32 &= b32 - 1;
      acc += d2A[d_];
    }
    acc += __shfl_xor(acc, 1); acc += __shfl_xor(acc, 2);
    if (h == 0)
      cA[s] = d2A[s] * (d2A[s] + acc) * rsf[kept[s]] * (1.0f / (float)KKEEP);
  }
  __syncthreads();

  // ---------------- Phase 11: wsum[k] = sum_s cA[s]*xnew[kept[s],k]; out ----------------
  {
    const int f = tid & 63, blk = tid >> 6;   // 16 blocks of 8 kept nodes
    float p = 0.f;
    for (int j = 0; j < 8; ++j) {
      const int s = blk * 8 + j;
      const int ks = kept[s];
      const int off = (ks << 6) + (((((f >> 2) ^ ks) ^ (ks >> 4)) & 15) << 2) + (f & 3);
      p += cA[s] * buf[off];
    }
    esc[blk * 64 + f] = p;
  }
  __syncthreads();
  if (tid < HIDD) {
    float s = 0.f;
#pragma unroll
    for (int b = 0; b < 16; ++b) s += esc[b * 64 + tid];
    wsum[tid] = s;
  }
  __syncthreads();
  if (tid < HIDD) {
    float o = b2[tid];
    for (int k = 0; k < HIDD; ++k) o += wsum[k] * W2[k * HIDD + tid];
    out[(size_t)g * HIDD + tid] = o;
  }
}

extern "C" void kernel_launch(void* const* d_in, const int* in_sizes, int n_in,
                              void* d_out, int out_size, void* d_ws, size_t ws_size,
                              hipStream_t stream) {
  (void)n_in; (void)out_size; (void)d_ws; (void)ws_size;
  const float* x    = (const float*)d_in[0];
  const int*   ei   = (const int*)d_in[1];
  // d_in[2] = batch (contiguous equal graphs; unused)
  const float* W1   = (const float*)d_in[3];
  const float* b1   = (const float*)d_in[4];
  const float* linW = (const float*)d_in[5];
  const float* linb = (const float*)d_in[6];
  const float* attW = (const float*)d_in[7];
  const float* attb = (const float*)d_in[8];
  const float* le1W = (const float*)d_in[9];
  const float* le1b = (const float*)d_in[10];
  const float* le2W = (const float*)d_in[11];
  const float* le3W = (const float*)d_in[12];
  const float* le3b = (const float*)d_in[13];
  const float* W2   = (const float*)d_in[14];
  const float* b2   = (const float*)d_in[15];
  const int Etot = in_sizes[1] / 2;   // 524288
  const int nGraphs = 256;

  asap_fused<<<dim3(nGraphs), dim3(NTH), 0, stream>>>(
      x, ei, W1, b1, linW, linb, attW, attb, le1W, le1b, le2W, le3W, le3b,
      W2, b2, (float*)d_out, Etot);
}

// Round 8
// 51.307 us; speedup vs baseline: 1.3096x; 1.1352x over previous
//
#include <hip/hip_runtime.h>

typedef float f4 __attribute__((ext_vector_type(4)));
typedef unsigned long long u64;

#define NPGL 256     // nodes per graph
#define EPGL 2048    // edges per graph
#define HIDD 64
#define KKEEP 128
#define NTH 1024
#define RSTR 72      // padded row stride in floats (72*4=288B)

// float offset of float4-chunk c (0..15) of row n — padded, NO swizzle:
// chunk offsets within an unrolled j-loop fold into ds_read immediates.
__device__ __forceinline__ int ro(int n, int c) { return n * RSTR + c * 4; }

__global__ void __launch_bounds__(NTH)
asap_fused(const float* __restrict__ x, const int* __restrict__ ei,
           const float* __restrict__ W1, const float* __restrict__ b1,
           const float* __restrict__ linW, const float* __restrict__ linb,
           const float* __restrict__ attW, const float* __restrict__ attb,
           const float* __restrict__ le1W, const float* __restrict__ le1b,
           const float* __restrict__ le2W,
           const float* __restrict__ le3W, const float* __restrict__ le3b,
           const float* __restrict__ W2, const float* __restrict__ b2,
           float* __restrict__ out, int Etot)
{
  const int g = blockIdx.x;
  const int tid = threadIdx.x;

  __shared__ __align__(16) float buf[NPGL * RSTR];   // 72KB: x -> h' -> h1 -> xnew
  __shared__ __align__(16) float mskf[4096];         // 16KB: Imask/Rmask/conn/kept...
  __shared__ __align__(16) float esc[EPGL];          // 8KB: exp scores / partials
  __shared__ __align__(8) unsigned char csrc[4096];  // 4KB padded CSR src (by dst)
  __shared__ unsigned short rowstU[NPGL + 1];        // unpadded row starts
  __shared__ unsigned short rowstP[NPGL + 1];        // 8-padded row starts
  __shared__ int cnt[NPGL];                          // counts -> cursors -> deg
  __shared__ float dinv_[NPGL];                      // conv1 norm -> LEConv c3
  __shared__ float sA[NPGL], sB[NPGL];
  __shared__ float rsf[NPGL];                        // fitness
  __shared__ float u_[HIDD], wsum[HIDD];
  __shared__ int scanw[4], scanwP[4];
  __shared__ float c0s;

  u64* Imask = (u64*)mskf;                 // [1024] = 8KB
  u64* Rmask = ((u64*)mskf) + 1024;        // [512]  = 4KB
  u64* conn  = ((u64*)mskf) + 1536;        // [256]  = 2KB
  int*   kept = (int*)(mskf + 3584);       // [128]
  float* d2A  = mskf + 3712;               // [128]
  float* cA   = mskf + 3840;               // [128]

  const int ebase = g * EPGL;
  const int nbase = g * NPGL;

  // ---------------- Phase 0: CSR build (padded) + x stage + Imask ----------------
  ((u64*)mskf)[tid] = 0ull;                          // zero Imask (8KB)
  if (tid < NPGL) { cnt[tid] = 0; ((u64*)mskf)[1536 + tid] = 0ull; }  // zero conn
  __syncthreads();

  int es[2], ed[2];
#pragma unroll
  for (int i = 0; i < 2; ++i) {
    const int e = tid + i * NTH;
    es[i] = ei[ebase + e] - nbase;
    ed[i] = ei[Etot + ebase + e] - nbase;
    atomicAdd(&cnt[ed[i]], 1);
  }
  // stage x -> buf (padded)
  {
    const f4* xg = (const f4*)(x + (size_t)nbase * HIDD);
#pragma unroll
    for (int ii = 0; ii < 4; ++ii) {
      const int i = tid + ii * NTH;
      *(f4*)&buf[ro(i >> 4, i & 15)] = xg[i];
    }
  }
  __syncthreads();

  int sU = 0, sP = 0, mU = 0;
  if (tid < NPGL) {                 // dual wave scan: unpadded + padded sizes
    mU = cnt[tid];
    const int mP = (mU + 7) & ~7;
    sU = mU; sP = mP;
#pragma unroll
    for (int off = 1; off < 64; off <<= 1) {
      const int uU = __shfl_up(sU, off, 64);
      const int uP = __shfl_up(sP, off, 64);
      if ((tid & 63) >= off) { sU += uU; sP += uP; }
    }
    if ((tid & 63) == 63) { scanw[tid >> 6] = sU; scanwP[tid >> 6] = sP; }
  }
  __syncthreads();
  if (tid < NPGL) {
    int aU = 0, aP = 0;
    const int w = tid >> 6;
    for (int ww = 0; ww < w; ++ww) { aU += scanw[ww]; aP += scanwP[ww]; }
    rowstU[tid + 1] = (unsigned short)(sU + aU);
    rowstP[tid + 1] = (unsigned short)(sP + aP);
    if (tid == 0) { rowstU[0] = 0; rowstP[0] = 0; }
    cnt[tid] = 0;                   // reset to use as arrival cursor
    dinv_[tid] = rsqrtf((float)mU + 1.0f);
  }
  if (tid < HIDD) {                 // u = lin_W @ attW[:64]
    float a = 0.f;
    for (int f = 0; f < HIDD; ++f) a += linW[tid * HIDD + f] * attW[f];
    u_[tid] = a;
  }
  if (tid == 0) {
    float a = 0.f;
    for (int f = 0; f < HIDD; ++f) a += linb[f] * attW[f];
    c0s = a + attb[0];
  }
  __syncthreads();

  // scatter into padded CSR + Imask bits
#pragma unroll
  for (int i = 0; i < 2; ++i) {
    const int j = atomicAdd(&cnt[ed[i]], 1);
    csrc[(int)rowstP[ed[i]] + j] = (unsigned char)es[i];
  }
  if (tid < NPGL) atomicOr(&Imask[tid * 4 + (tid >> 6)], 1ull << (tid & 63));
#pragma unroll
  for (int i = 0; i < 2; ++i)
    atomicOr(&Imask[ed[i] * 4 + (es[i] >> 6)], 1ull << (es[i] & 63));
  __syncthreads();

  // ---------------- Phase 1: h' = dinv * (x @ W1) (W1 via scalar loads) ----------------
  {
    const int wv = tid >> 6;
    const int r  = ((wv & 3) << 6) + (tid & 63);
    const int fc = __builtin_amdgcn_readfirstlane(wv >> 2);
    const float* __restrict__ Wg = W1 + fc * 16;
    f4 acc[4];
#pragma unroll
    for (int c = 0; c < 4; ++c) acc[c] = f4{0.f, 0.f, 0.f, 0.f};
#pragma unroll
    for (int p = 0; p < 4; ++p) {
      f4 xa[4];
#pragma unroll
      for (int c = 0; c < 4; ++c) xa[c] = *(const f4*)&buf[ro(r, p * 4 + c)];
#pragma unroll
      for (int kk = 0; kk < 16; ++kk) {
        const int k = p * 16 + kk;
        const float xv = ((const float*)xa)[kk];
        const float* __restrict__ Wk = Wg + k * HIDD;   // uniform -> s_load
#pragma unroll
        for (int c = 0; c < 4; ++c)
          acc[c] += xv * *(const f4*)(Wk + c * 4);
      }
    }
    const float dv = dinv_[r];
    __syncthreads();                // all x reads before h' overwrite
#pragma unroll
    for (int c = 0; c < 4; ++c) *(f4*)&buf[ro(r, fc * 4 + c)] = acc[c] * dv;
  }
  __syncthreads();

  // ---------------- Phase 2: h1 = relu(dd*(sum h' + self) + b1) + sB fold ----------------
  {
    const int d = tid >> 2, hh = tid & 3;
    const float dd = dinv_[d];
    const int deg = cnt[d];
    const int p0 = rowstP[d];
    const int hb = ro(0, hh);       // hh*4
    f4 acc[4], acc2[4];
#pragma unroll
    for (int j = 0; j < 4; ++j) {
      acc[j] = *(const f4*)&buf[ro(d, hh) + j * 16];   // self h'
      acc2[j] = f4{0.f, 0.f, 0.f, 0.f};
    }
    const int nb = deg >> 3;
    int j8 = 0;
    for (int b = 0; b < nb; ++b, j8 += 8) {
      const u64 bits = *(const u64*)(csrc + p0 + j8);
#pragma unroll
      for (int t = 0; t < 8; ++t) {
        const int s = (int)((bits >> (8 * t)) & 255);
        const int base = s * RSTR + hb;
        if (t & 1) {
#pragma unroll
          for (int j = 0; j < 4; ++j) acc2[j] += *(const f4*)&buf[base + j * 16];
        } else {
#pragma unroll
          for (int j = 0; j < 4; ++j) acc[j] += *(const f4*)&buf[base + j * 16];
        }
      }
    }
    const int rem = deg & 7;
    if (rem) {
      const u64 bits = *(const u64*)(csrc + p0 + j8);
      for (int t = 0; t < rem; ++t) {
        const int s = (int)((bits >> (8 * t)) & 255);
        const int base = s * RSTR + hb;
#pragma unroll
        for (int j = 0; j < 4; ++j) acc[j] += *(const f4*)&buf[base + j * 16];
      }
    }
    float sBp = 0.f;
#pragma unroll
    for (int j = 0; j < 4; ++j) {
      acc[j] = (acc[j] + acc2[j]) * dd + *(const f4*)&b1[4 * (hh + 4 * j)];
      acc[j] = __builtin_elementwise_max(acc[j], f4{0.f, 0.f, 0.f, 0.f});
      const f4 aw = *(const f4*)&attW[HIDD + 4 * (hh + 4 * j)];
      sBp += acc[j].x * aw.x + acc[j].y * aw.y + acc[j].z * aw.z + acc[j].w * aw.w;
    }
    sBp += __shfl_xor(sBp, 1); sBp += __shfl_xor(sBp, 2);
    if (hh == 0) sB[d] = sBp;
    __syncthreads();
#pragma unroll
    for (int j = 0; j < 4; ++j) *(f4*)&buf[ro(d, hh) + j * 16] = acc[j];
  }
  __syncthreads();

  // ---------------- Phase 3+4+5: seg-max -> sA -> softmax -> xnew ----------------
  {
    const int d = tid >> 2, hh = tid & 3;
    const int deg = cnt[d];
    const int p0 = rowstP[d];
    const int q0 = rowstU[d];
    const int hb = hh * 4;
    f4 own[4], mx[4], mx2[4];
#pragma unroll
    for (int j = 0; j < 4; ++j) {
      own[j] = *(const f4*)&buf[ro(d, hh) + j * 16];
      mx[j] = own[j];
      mx2[j] = own[j];
    }
    // seg-max gather (indices batched in regs)
    const int nb = deg >> 3;
    int j8 = 0;
    for (int b = 0; b < nb; ++b, j8 += 8) {
      const u64 bits = *(const u64*)(csrc + p0 + j8);
#pragma unroll
      for (int t = 0; t < 8; ++t) {
        const int s = (int)((bits >> (8 * t)) & 255);
        const int base = s * RSTR + hb;
        if (t & 1) {
#pragma unroll
          for (int j = 0; j < 4; ++j)
            mx2[j] = __builtin_elementwise_max(mx2[j], *(const f4*)&buf[base + j * 16]);
        } else {
#pragma unroll
          for (int j = 0; j < 4; ++j)
            mx[j] = __builtin_elementwise_max(mx[j], *(const f4*)&buf[base + j * 16]);
        }
      }
    }
    const int rem = deg & 7;
    if (rem) {
      const u64 bits = *(const u64*)(csrc + p0 + j8);
      for (int t = 0; t < rem; ++t) {
        const int s = (int)((bits >> (8 * t)) & 255);
        const int base = s * RSTR + hb;
#pragma unroll
        for (int j = 0; j < 4; ++j)
          mx[j] = __builtin_elementwise_max(mx[j], *(const f4*)&buf[base + j * 16]);
      }
    }
    float sAv = 0.f;
#pragma unroll
    for (int j = 0; j < 4; ++j) {
      mx[j] = __builtin_elementwise_max(mx[j], mx2[j]);
      const f4 uu = *(const f4*)&u_[4 * (hh + 4 * j)];
      sAv += mx[j].x * uu.x + mx[j].y * uu.y + mx[j].z * uu.z + mx[j].w * uu.w;
    }
    sAv += __shfl_xor(sAv, 1); sAv += __shfl_xor(sAv, 2);
    const float sa = c0s + sAv;
    // softmax max via monotonicity of leaky_relu: max sc = leaky(sa + max sB)
    const float sBd = sB[d];
    float mxB = sBd;
#pragma unroll 4
    for (int t = hh; t < deg; t += 4) mxB = fmaxf(mxB, sB[csrc[p0 + t]]);
    mxB = fmaxf(mxB, __shfl_xor(mxB, 1));
    mxB = fmaxf(mxB, __shfl_xor(mxB, 2));
    float mxv = sa + mxB;
    mxv = mxv >= 0.f ? mxv : 0.2f * mxv;
    float sum = 0.f;
#pragma unroll 4
    for (int t = hh; t < deg; t += 4) {
      float sc = sa + sB[csrc[p0 + t]];
      sc = sc >= 0.f ? sc : 0.2f * sc;
      const float e = __expf(sc - mxv);
      esc[q0 + t] = e;
      sum += e;
    }
    sum += __shfl_xor(sum, 1); sum += __shfl_xor(sum, 2);
    float scS = sa + sBd;
    scS = scS >= 0.f ? scS : 0.2f * scS;
    const float esf = __expf(scS - mxv);
    const float rs = 1.0f / (esf + sum + 1e-16f);
    // ensure this wave's esc writes are complete before cross-lane reads
    asm volatile("s_waitcnt lgkmcnt(0)" ::: "memory");
    // weighted gather
    f4 a[4], a2[4];
#pragma unroll
    for (int j = 0; j < 4; ++j) { a[j] = esf * own[j]; a2[j] = f4{0.f, 0.f, 0.f, 0.f}; }
    j8 = 0;
    for (int b = 0; b < nb; ++b, j8 += 8) {
      const u64 bits = *(const u64*)(csrc + p0 + j8);
#pragma unroll
      for (int t = 0; t < 8; ++t) {
        const int s = (int)((bits >> (8 * t)) & 255);
        const float e = esc[q0 + j8 + t];
        const int base = s * RSTR + hb;
        if (t & 1) {
#pragma unroll
          for (int j = 0; j < 4; ++j) a2[j] += e * *(const f4*)&buf[base + j * 16];
        } else {
#pragma unroll
          for (int j = 0; j < 4; ++j) a[j] += e * *(const f4*)&buf[base + j * 16];
        }
      }
    }
    if (rem) {
      const u64 bits = *(const u64*)(csrc + p0 + j8);
      for (int t = 0; t < rem; ++t) {
        const int s = (int)((bits >> (8 * t)) & 255);
        const float e = esc[q0 + j8 + t];
        const int base = s * RSTR + hb;
#pragma unroll
        for (int j = 0; j < 4; ++j) a[j] += e * *(const f4*)&buf[base + j * 16];
      }
    }
#pragma unroll
    for (int j = 0; j < 4; ++j) a[j] = (a[j] + a2[j]) * rs;
    __syncthreads();
#pragma unroll
    for (int j = 0; j < 4; ++j) *(f4*)&buf[ro(d, hh) + j * 16] = a[j];
  }
  __syncthreads();

  // ---------------- Phase 6: LEConv dots + fitness ----------------
  {
    const int n = tid >> 2, q = tid & 3;
    float av = 0.f, bv = 0.f, cv = 0.f;
#pragma unroll
    for (int j = 0; j < 4; ++j) {
      const int c = q + 4 * j;
      const f4 v = *(const f4*)&buf[ro(n, q) + j * 16];
      const int k = c * 4;
      av += v.x * le1W[k] + v.y * le1W[k + 1] + v.z * le1W[k + 2] + v.w * le1W[k + 3];
      bv += v.x * le2W[k] + v.y * le2W[k + 1] + v.z * le2W[k + 2] + v.w * le2W[k + 3];
      cv += v.x * le3W[k] + v.y * le3W[k + 1] + v.z * le3W[k + 2] + v.w * le3W[k + 3];
    }
    av += __shfl_xor(av, 1); av += __shfl_xor(av, 2);
    bv += __shfl_xor(bv, 1); bv += __shfl_xor(bv, 2);
    cv += __shfl_xor(cv, 1); cv += __shfl_xor(cv, 2);
    if (q == 0) {
      sA[n] = av + le1b[0];
      sB[n] = bv;
      dinv_[n] = cv + le3b[0];
    }
  }
  __syncthreads();
  {
    const int d = tid >> 2, q = tid & 3;
    const int deg = cnt[d];
    const int p0 = rowstP[d];
    float fp = 0.f;
#pragma unroll 4
    for (int t = q; t < deg; t += 4) fp += sA[csrc[p0 + t]];
    fp += __shfl_xor(fp, 1); fp += __shfl_xor(fp, 2);
    if (q == 0) {
      float f = sA[d] + fp;
      f -= (float)(deg + 1) * sB[d];
      f += dinv_[d];
      float sg;
      if (f >= 0.f) sg = 1.f / (1.f + expf(-f));
      else { const float t2 = expf(f); sg = t2 / (1.f + t2); }
      rsf[d] = sg;
    }
  }
  __syncthreads();

  // ---------------- Phase 7: top-K by rank ----------------
  {
    const int n = tid >> 2, q = tid & 3;
    const float fn = rsf[n];
    int r = 0;
    for (int m = q * 64; m < q * 64 + 64; ++m) {
      const float fm = rsf[m];
      r += ((fm > fn) || (fm == fn && m < n)) ? 1 : 0;
    }
    r += __shfl_xor(r, 1); r += __shfl_xor(r, 2);
    if (q == 0 && r < KKEEP) kept[r] = n;
  }
  __syncthreads();

  // ---------------- Phase 9: Rmask / conn ----------------
  if (tid < KKEEP * 4) {
    const int q = tid >> 2, w = tid & 3;
    const int kq = kept[q];
    u64 acc = 0ull;
#pragma unroll
    for (int ww = 0; ww < 4; ++ww) {
      u64 bits = Imask[kq * 4 + ww];
      while (bits) {
        const int m = (ww << 6) + __builtin_ctzll(bits);
        bits &= bits - 1;
        acc |= Imask[m * 4 + w];
      }
    }
    Rmask[q * 4 + w] = acc;
  }
  __syncthreads();
  if (tid < KKEEP * 4) {
    const int p = tid >> 2, wb = tid & 3;
    const int kp = kept[p];
    const u64 I0 = Imask[kp * 4 + 0], I1 = Imask[kp * 4 + 1],
              I2 = Imask[kp * 4 + 2], I3 = Imask[kp * 4 + 3];
    u64 bits = 0ull;
    for (int j = 0; j < 32; ++j) {
      const int q = wb * 32 + j;
      if (q == p) continue;
      const u64* R = &Rmask[q * 4];
      if ((I0 & R[0]) | (I1 & R[1]) | (I2 & R[2]) | (I3 & R[3]))
        bits |= 1ull << (q & 63);
    }
    atomicOr(&conn[p * 2 + (wb >> 1)], bits);
  }
  __syncthreads();

  // ---------------- Phase 10: deg2, d2 (512 thr), cA (512 thr) ----------------
  if (tid < KKEEP * 4) {
    const int q = tid >> 2, h = tid & 3;
    const int w = q >> 6, sh = q & 63;
    int c = 0;
    for (int p = h * 32; p < h * 32 + 32; ++p)
      c += (int)((conn[p * 2 + w] >> sh) & 1ull);
    c += __shfl_xor(c, 1); c += __shfl_xor(c, 2);
    if (h == 0) d2A[q] = rsqrtf((float)(c + 1));
  }
  __syncthreads();
  if (tid < KKEEP * 4) {
    const int s = tid >> 2, h = tid & 3;
    unsigned int b32 = (unsigned int)(conn[s * 2 + (h >> 1)] >> (32 * (h & 1)));
    const int base = ((h >> 1) << 6) + ((h & 1) << 5);
    float acc = 0.f;
    while (b32) {
      const int d_ = base + __builtin_ctz(b32);
      b32 &= b32 - 1;
      acc += d2A[d_];
    }
    acc += __shfl_xor(acc, 1); acc += __shfl_xor(acc, 2);
    if (h == 0)
      cA[s] = d2A[s] * (d2A[s] + acc) * rsf[kept[s]] * (1.0f / (float)KKEEP);
  }
  __syncthreads();

  // ---------------- Phase 11: wsum[k] = sum_s cA[s]*xnew[kept[s],k]; out ----------------
  {
    const int f = tid & 63, blk = tid >> 6;   // 16 blocks of 8 kept nodes
    float p = 0.f;
    for (int j = 0; j < 8; ++j) {
      const int s = blk * 8 + j;
      const int ks = kept[s];
      p += cA[s] * buf[ks * RSTR + f];        // consecutive lanes: conflict-free
    }
    esc[blk * 64 + f] = p;
  }
  __syncthreads();
  if (tid < HIDD) {
    float s = 0.f;
#pragma unroll
    for (int b = 0; b < 16; ++b) s += esc[b * 64 + tid];
    wsum[tid] = s;
  }
  __syncthreads();
  if (tid < HIDD) {
    float o = b2[tid];
    for (int k = 0; k < HIDD; ++k) o += wsum[k] * W2[k * HIDD + tid];
    out[(size_t)g * HIDD + tid] = o;
  }
}

extern "C" void kernel_launch(void* const* d_in, const int* in_sizes, int n_in,
                              void* d_out, int out_size, void* d_ws, size_t ws_size,
                              hipStream_t stream) {
  (void)n_in; (void)out_size; (void)d_ws; (void)ws_size;
  const float* x    = (const float*)d_in[0];
  const int*   ei   = (const int*)d_in[1];
  // d_in[2] = batch (contiguous equal graphs; unused)
  const float* W1   = (const float*)d_in[3];
  const float* b1   = (const float*)d_in[4];
  const float* linW = (const float*)d_in[5];
  const float* linb = (const float*)d_in[6];
  const float* attW = (const float*)d_in[7];
  const float* attb = (const float*)d_in[8];
  const float* le1W = (const float*)d_in[9];
  const float* le1b = (const float*)d_in[10];
  const float* le2W = (const float*)d_in[11];
  const float* le3W = (const float*)d_in[12];
  const float* le3b = (const float*)d_in[13];
  const float* W2   = (const float*)d_in[14];
  const float* b2   = (const float*)d_in[15];
  const int Etot = in_sizes[1] / 2;   // 524288
  const int nGraphs = 256;

  asap_fused<<<dim3(nGraphs), dim3(NTH), 0, stream>>>(
      x, ei, W1, b1, linW, linb, attW, attb, le1W, le1b, le2W, le3W, le3b,
      W2, b2, (float*)d_out, Etot);
}